// Round 2
// baseline (217.584 us; speedup 1.0000x reference)
//
#include <hip/hip_runtime.h>
#include <cstdint>

// ECT loss via histogram factorization.
// A[b,c,r,d] = sum_p dw[b,p,c] * sigmoid(8*(lin_r - <x_p, v_d>))
//   step 1: lerp-bin dw into H[d][bin][bc] over nh with bin width = lin_step/8
//   step 2: A[r,d,bc] = sum_b H[d][b][bc] * sigmoid(S*(8r - b));  loss = mean(A^2)
// c=2 channel reconstructed as -(c0+c1) (softmax and onehot both sum to 1).

#define P_TOT 110592
#define NB 505                  // bins: b=0..504, t_b = -rad + b*(S/8); t_504 = +rad
#define HSTRIDE 5               // padded words per bin in LDS hist (4 bc + 1 pad)
#define HBINS (NB + 1)          // row pad
#define RADIUS 1.9052558f       // 1.1*sqrt(3)
#define SSTEP (2.0f * RADIUS / 63.0f)
#define INVH (8.0f / SSTEP)     // 1 / (S/8)

__device__ __forceinline__ uint32_t rotl32(uint32_t x, int d) {
  return (x << d) | (x >> (32 - d));
}

// threefry2x32 with key = (0, 17)  [jax.random.key(17)] — verified bit-exact R1
__device__ __forceinline__ void threefry_0_17(uint32_t x0, uint32_t x1,
                                              uint32_t& o0, uint32_t& o1) {
  const uint32_t ks0 = 0u, ks1 = 17u, ks2 = 0x1BD11BDAu ^ 0u ^ 17u;
  x0 += ks0; x1 += ks1;
#define R4(a,b,c,dd) \
  x0 += x1; x1 = rotl32(x1,(a)); x1 ^= x0; \
  x0 += x1; x1 = rotl32(x1,(b)); x1 ^= x0; \
  x0 += x1; x1 = rotl32(x1,(c)); x1 ^= x0; \
  x0 += x1; x1 = rotl32(x1,(dd)); x1 ^= x0;
  R4(13,15,26,6)   x0 += ks1; x1 += ks2 + 1u;
  R4(17,29,16,24)  x0 += ks2; x1 += ks0 + 2u;
  R4(13,15,26,6)   x0 += ks0; x1 += ks1 + 3u;
  R4(17,29,16,24)  x0 += ks1; x1 += ks2 + 4u;
  R4(13,15,26,6)   x0 += ks2; x1 += ks0 + 5u;
#undef R4
  o0 = x0; o1 = x1;
}

// XLA ErfInv32 (Giles polynomial) — verified bit-exact R1
__device__ __forceinline__ float erfinv_f32(float x) {
  float w = -log1pf(-x * x);
  float p;
  if (w < 5.0f) {
    w = w - 2.5f;
    p = 2.81022636e-08f;
    p = fmaf(p, w, 3.43273939e-07f);
    p = fmaf(p, w, -3.5233877e-06f);
    p = fmaf(p, w, -4.39150654e-06f);
    p = fmaf(p, w, 0.00021858087f);
    p = fmaf(p, w, -0.00125372503f);
    p = fmaf(p, w, -0.00417768164f);
    p = fmaf(p, w, 0.246640727f);
    p = fmaf(p, w, 1.50140941f);
  } else {
    w = sqrtf(w) - 3.0f;
    p = -0.000200214257f;
    p = fmaf(p, w, 0.000100950558f);
    p = fmaf(p, w, 0.00134934322f);
    p = fmaf(p, w, 0.000337081863f);
    p = fmaf(p, w, 0.00573950773f);
    p = fmaf(p, w, -0.0076224613f);
    p = fmaf(p, w, 0.00943887047f);
    p = fmaf(p, w, 1.00167406f);
    p = fmaf(p, w, 2.83297682f);
  }
  return p * x;
}

// grid = 4 d-groups x 64 voxel-chunks = 256 blocks, 512 threads.
// Block bins 1728 voxels against its 8 directions into an 81KB LDS histogram,
// then atomically merges into global G[32][NB][4].
__global__ __launch_bounds__(512) void ect_bin(
    const float* __restrict__ pred, const int* __restrict__ tgt,
    float* __restrict__ G) {
  __shared__ float dirs[96];                       // [3][32]
  __shared__ float hist[8 * HBINS * HSTRIDE];      // 20240 words = 80.96 KB

  int t = threadIdx.x;
  int grp = blockIdx.x & 3;
  int chunk = blockIdx.x >> 2;

  if (t < 96) {
    uint32_t o0, o1;
    threefry_0_17(0u, (uint32_t)t, o0, o1);
    uint32_t bits = o0 ^ o1;
    float u = __uint_as_float((bits >> 9) | 0x3F800000u) - 1.0f;
    const float lo = -0.99999994f;
    float v = fmaf(u, 2.0f, lo);
    v = fmaxf(v, lo);
    dirs[t] = 1.41421356237f * erfinv_f32(v);
  }
  __syncthreads();
  if (t < 32) {
    float a = dirs[t], b = dirs[32 + t], c = dirs[64 + t];
    float n = fmaxf(sqrtf(a * a + b * b + c * c), 1e-12f);
    dirs[t] = a / n; dirs[32 + t] = b / n; dirs[64 + t] = c / n;
  }
  for (int i = t; i < 8 * HBINS * HSTRIDE; i += 512) hist[i] = 0.0f;
  __syncthreads();

  float dx[8], dy[8], dz[8];
#pragma unroll
  for (int k = 0; k < 8; k++) {
    int d = grp * 8 + k;
    dx[k] = dirs[d]; dy[k] = dirs[32 + d]; dz[k] = dirs[64 + d];
  }

  int base = chunk * 1728;
  for (int i = t; i < 1728; i += 512) {
    int p = base + i;
    int ix = p / 2304; int rem = p - ix * 2304;
    int iy = rem / 48; int iz = rem - iy * 48;
    const float delta = 2.0f / 47.0f;
    float cx = (float)ix * delta - 1.0f;
    float cy = (float)iy * delta - 1.0f;
    float cz = (float)iz * delta - 1.0f;

    float w[4];
#pragma unroll
    for (int b = 0; b < 2; b++) {
      const float* pb = pred + b * (3 * P_TOT) + p;
      float x0 = pb[0], x1 = pb[P_TOT], x2 = pb[2 * P_TOT];
      float m = fmaxf(x0, fmaxf(x1, x2));
      float e0 = __expf(x0 - m), e1 = __expf(x1 - m), e2 = __expf(x2 - m);
      float inv = 1.0f / (e0 + e1 + e2);
      int tg = tgt[b * P_TOT + p];
      w[b * 2 + 0] = e0 * inv - ((tg == 0) ? 1.0f : 0.0f);
      w[b * 2 + 1] = e1 * inv - ((tg == 1) ? 1.0f : 0.0f);
    }

#pragma unroll
    for (int k = 0; k < 8; k++) {
      float nh = fmaf(cz, dz[k], fmaf(cy, dy[k], cx * dx[k]));
      float binf = (nh + RADIUS) * INVH;
      float fl = floorf(binf);
      int ib = (int)fl;
      float fr = binf - fl;
      ib = (ib < 0) ? 0 : ((ib > NB - 2) ? (NB - 2) : ib);
      float w0 = 1.0f - fr;
      int a0 = (k * HBINS + ib) * HSTRIDE;
      int a1 = a0 + HSTRIDE;
#pragma unroll
      for (int bc = 0; bc < 4; bc++) {
        atomicAdd(&hist[a0 + bc], w[bc] * w0);
        atomicAdd(&hist[a1 + bc], w[bc] * fr);
      }
    }
  }
  __syncthreads();

  // merge LDS hist -> global G
  for (int idx = t; idx < 8 * NB * 4; idx += 512) {
    int d = idx / (NB * 4);
    int rem = idx - d * (NB * 4);
    int bin = rem >> 2;
    int bc = rem & 3;
    float v = hist[(d * HBINS + bin) * HSTRIDE + bc];
    if (v != 0.0f)
      atomicAdd(&G[((size_t)(grp * 8 + d) * NB + bin) * 4 + bc], v);
  }
}

// grid = 32 d x 8 r-octets = 256 blocks, 256 threads = (j:8) x (sub:32).
// Computes A[r,d,bc] by convolving G with sigmoid, squares, atomicAdds loss.
__global__ __launch_bounds__(256) void ect_conv(
    const float* __restrict__ G, float* __restrict__ out) {
  __shared__ float accs[8][4];
  int t = threadIdx.x;
  int d = blockIdx.x >> 3;
  int rg = blockIdx.x & 7;
  int j = t & 7;
  int sub = t >> 3;
  if (t < 32) accs[t >> 2][t & 3] = 0.0f;
  __syncthreads();

  int r = rg * 8 + j;
  float a0 = 0.f, a1 = 0.f, a2 = 0.f, a3 = 0.f;
  const float* gd = G + (size_t)d * NB * 4;
#pragma unroll 4
  for (int i = 0; i < 16; i++) {
    int b = sub * 16 + i;
    if (b < NB) {
      float4 g = *(const float4*)(gd + (size_t)b * 4);
      float x = SSTEP * (float)(8 * r - b);
      float sg = 1.0f / (1.0f + __expf(-x));
      a0 = fmaf(g.x, sg, a0); a1 = fmaf(g.y, sg, a1);
      a2 = fmaf(g.z, sg, a2); a3 = fmaf(g.w, sg, a3);
    }
  }
  atomicAdd(&accs[j][0], a0);
  atomicAdd(&accs[j][1], a1);
  atomicAdd(&accs[j][2], a2);
  atomicAdd(&accs[j][3], a3);
  __syncthreads();

  if (t < 8) {
    float b0c0 = accs[t][0], b0c1 = accs[t][1];
    float b1c0 = accs[t][2], b1c1 = accs[t][3];
    float s = b0c0 * b0c0 + b0c1 * b0c1 + (b0c0 + b0c1) * (b0c0 + b0c1)
            + b1c0 * b1c0 + b1c1 * b1c1 + (b1c0 + b1c1) * (b1c0 + b1c1);
    atomicAdd(out, s * (1.0f / 12288.0f));
  }
}

extern "C" void kernel_launch(void* const* d_in, const int* in_sizes, int n_in,
                              void* d_out, int out_size, void* d_ws, size_t ws_size,
                              hipStream_t stream) {
  const float* pred = (const float*)d_in[0];
  const int* tgt = (const int*)d_in[1];
  float* G = (float*)d_ws;                     // 32*NB*4 floats = 258,560 B
  float* out = (float*)d_out;

  hipMemsetAsync(out, 0, sizeof(float), stream);
  hipMemsetAsync(G, 0, (size_t)32 * NB * 4 * sizeof(float), stream);
  hipLaunchKernelGGL(ect_bin, dim3(256), dim3(512), 0, stream, pred, tgt, G);
  hipLaunchKernelGGL(ect_conv, dim3(256), dim3(256), 0, stream, G, out);
}